// Round 11
// baseline (481.822 us; speedup 1.0000x reference)
//
#include <hip/hip_runtime.h>
#include <hip/hip_bf16.h>

#define NN 4096
#define IN_DIM 512
#define NH 8
#define DD 64
#define HD 512    // NH*DD
#define QCAP 128  // per-quarter cap: Binomial(1024,.05) mean 51 sigma 7 -> +11 sigma
#define RCAP 448  // per-row cap: mean 205 sigma 14 -> +17 sigma

// Workspace: d1b 4MB + Ab 4MB + Wb 0.5MB + src/trg 0.25MB ~= 8.75 MB
// (R3 lesson: stay well under ~12 MB; R7 proved 8.75 MB works).

typedef __attribute__((ext_vector_type(8))) short short8;
typedef __attribute__((ext_vector_type(4))) float f32x4;
typedef __attribute__((ext_vector_type(2))) float f32x2;

static __device__ __forceinline__ unsigned short f2bf(float x) {
    __hip_bfloat16 h = __float2bfloat16(x);
    return *reinterpret_cast<unsigned short*>(&h);
}

// ---------------- K0: fp32 -> bf16 cast of data and W (one launch) -----------
// Cast ONCE here; R8's fused-into-GEMM cast paid 64x-redundant conversion.
__global__ __launch_bounds__(256) void k_cast2(const float* __restrict__ inA,
                                               unsigned short* __restrict__ outA,
                                               int n4A,
                                               const float* __restrict__ inB,
                                               unsigned short* __restrict__ outB,
                                               int n4B) {
    int t = blockIdx.x * 256 + threadIdx.x;
    const float* in;
    unsigned short* out;
    if (t < n4A) {
        in = inA; out = outA;
    } else {
        t -= n4A;
        if (t >= n4B) return;
        in = inB; out = outB;
    }
    float4 v = ((const float4*)in)[t];
    ushort4 o;
    o.x = f2bf(v.x); o.y = f2bf(v.y); o.z = f2bf(v.z); o.w = f2bf(v.w);
    ((ushort4*)out)[t] = o;
}

// ---------------- K1: GEMM (bf16 MFMA) + fused src/trg projection ------------
// 64n x 64m per WG; m-tile == one head h = blockIdx.x. Fragments straight
// from global (k-major). C/D: col=lane&15, row=(lane>>4)*4+reg (m89-verified).
__global__ __launch_bounds__(256) void k_gemm_fused(const unsigned short* __restrict__ Ab,
                                                    const unsigned short* __restrict__ Wb,
                                                    const float* __restrict__ bias,
                                                    const float* __restrict__ sp,
                                                    const float* __restrict__ tp,
                                                    unsigned short* __restrict__ Cb,
                                                    float* __restrict__ src,
                                                    float* __restrict__ trg) {
    const int lane = threadIdx.x & 63;
    const int w = threadIdx.x >> 6;
    const int col = lane & 15;
    const int quad = lane >> 4;
    const int koff = quad * 8;
    const int h = blockIdx.x;
    const int m0 = h * 64;
    const int n0 = blockIdx.y * 64;

    const short8* ap  = (const short8*)(Ab + (size_t)(n0 + w * 16 + col) * IN_DIM + koff);
    const short8* bp0 = (const short8*)(Wb + (size_t)(m0 +  0 + col) * IN_DIM + koff);
    const short8* bp1 = (const short8*)(Wb + (size_t)(m0 + 16 + col) * IN_DIM + koff);
    const short8* bp2 = (const short8*)(Wb + (size_t)(m0 + 32 + col) * IN_DIM + koff);
    const short8* bp3 = (const short8*)(Wb + (size_t)(m0 + 48 + col) * IN_DIM + koff);

    f32x4 acc0 = {0.f, 0.f, 0.f, 0.f}, acc1 = acc0, acc2 = acc0, acc3 = acc0;

#pragma unroll 4
    for (int ks = 0; ks < 16; ks++) {
        short8 a  = ap[ks * 4];
        short8 b0 = bp0[ks * 4];
        short8 b1 = bp1[ks * 4];
        short8 b2 = bp2[ks * 4];
        short8 b3 = bp3[ks * 4];
        acc0 = __builtin_amdgcn_mfma_f32_16x16x32_bf16(a, b0, acc0, 0, 0, 0);
        acc1 = __builtin_amdgcn_mfma_f32_16x16x32_bf16(a, b1, acc1, 0, 0, 0);
        acc2 = __builtin_amdgcn_mfma_f32_16x16x32_bf16(a, b2, acc2, 0, 0, 0);
        acc3 = __builtin_amdgcn_mfma_f32_16x16x32_bf16(a, b3, acc3, 0, 0, 0);
    }

    const int rbase = n0 + w * 16 + quad * 4;
    f32x4 accs[4] = {acc0, acc1, acc2, acc3};
    float ps[4] = {0.f, 0.f, 0.f, 0.f};
    float pt[4] = {0.f, 0.f, 0.f, 0.f};
#pragma unroll
    for (int mt = 0; mt < 4; mt++) {
        const int m = m0 + mt * 16 + col;
        const float bv  = bias[m];
        const float spv = sp[m];
        const float tpv = tp[m];
#pragma unroll
        for (int r = 0; r < 4; r++) {
            float v = accs[mt][r] + bv;
            Cb[(size_t)(rbase + r) * HD + m] = f2bf(v);
            ps[r] += v * spv;
            pt[r] += v * tpv;
        }
    }
#pragma unroll
    for (int off = 1; off <= 8; off <<= 1) {
#pragma unroll
        for (int r = 0; r < 4; r++) {
            ps[r] += __shfl_xor(ps[r], off, 64);
            pt[r] += __shfl_xor(pt[r], off, 64);
        }
    }
    if (col < 4)
        src[(rbase + col) * 8 + h] = ps[col];
    else if (col < 8)
        trg[(rbase + col - 4) * 8 + h] = pt[col - 4];
}

// ---------------- K2: fused edge-scan + 2-edge-split gather attention --------
// One WG (4 waves) per row i = rowbase + blockIdx.x. Launched twice (2048 rows
// each) so every dispatch is ~25-30 us: drops the rocprof top-5 cutoff and
// exposes any hidden-fat kernel (diagnostic for the ~100 us residual).
//  phase 1: per-wave ballot-scan of a conn quarter into LDS segment.
//  phase 1b: compact to one list + 8 sentinels (no clamps needed anywhere).
//  phase 2: wave w gathers balanced range; lane = (e, h, d4): half-wave e
//           processes edge kbeg+2*kp+e, lane holds 32B (16 bf16) of V row.
//           DEPTH-4 rotating pipeline (8 edges in flight) to cover L2/L3
//           latency (R10 showed VALU cut didn't help -> latency-bound).
//  phase 3: shfl_xor(32) cross-half combine, LDS cross-wave combine,
//           divide once, store.
// conn==0.0f exactly marks kept edges; |e|<~6 so no max-subtraction needed.
__global__ __launch_bounds__(256) void k_rowattn(const float* __restrict__ conn,
                                                 const float* __restrict__ src,
                                                 const float* __restrict__ trg,
                                                 const unsigned short* __restrict__ d1b,
                                                 float* __restrict__ out,
                                                 int rowbase) {
    __shared__ unsigned short seg[4][QCAP];
    __shared__ unsigned short elist[RCAP + 8];
    __shared__ int wcnt[4];
    __shared__ float cbuf[3][32][17];   // waves 1..3 deposit acc[16]+lsum
    const int w = threadIdx.x >> 6, lane = threadIdx.x & 63;
    const int i = rowbase + blockIdx.x;

    // ---- phase 1: scan this wave's quarter of the conn row ----
    const float* crow = conn + (size_t)i * NN + w * 1024;
    int cnt = 0;
#pragma unroll
    for (int c0 = 0; c0 < 1024; c0 += 256) {
        float4 c = *(const float4*)(crow + c0 + lane * 4);
        float cv[4] = {c.x, c.y, c.z, c.w};
#pragma unroll
        for (int q = 0; q < 4; q++) {
            bool edge = (cv[q] == 0.0f);
            unsigned long long mask = __ballot(edge);
            int pre = __popcll(mask & ((1ull << lane) - 1ull));
            int pos = cnt + pre;
            if (edge && pos < QCAP)
                seg[w][pos] = (unsigned short)(w * 1024 + c0 + lane * 4 + q);
            cnt += __popcll(mask);
        }
    }
    if (cnt > QCAP) cnt = QCAP;
    if (lane == 0) wcnt[w] = cnt;
    __syncthreads();

    // ---- phase 1b: compact into one contiguous list + 8 sentinels ----
    const int c0n = wcnt[0], c1n = wcnt[1], c2n = wcnt[2], c3n = wcnt[3];
    int tot = c0n + c1n + c2n + c3n;
    if (tot > RCAP) tot = RCAP;   // (unreachable in practice)
    const int base = (w == 0) ? 0 : (w == 1) ? c0n
                   : (w == 2) ? c0n + c1n : c0n + c1n + c2n;
    for (int k = lane; k < cnt && base + k < RCAP; k += 64)
        elist[base + k] = seg[w][k];
    __syncthreads();
    if (threadIdx.x < 8)
        elist[tot + threadIdx.x] = (tot > 0) ? elist[tot - 1] : (unsigned short)0;
    __syncthreads();

    // ---- phase 2: balanced gather, 2 edges/iter, depth-4 pipeline ----
    const int e = lane >> 5;          // which edge of the pair
    const int l32 = lane & 31;
    const int h = l32 >> 2;           // 8 heads
    const int d4 = l32 & 3;           // 4 chunks of 16 bf16
    const float sh = src[i * 8 + h];
    const unsigned voffB = (unsigned)(h * 128 + d4 * 32);
    const unsigned char* vb = (const unsigned char*)d1b;
    const int kbeg = (tot * w) >> 2;
    const int kend = (tot * (w + 1)) >> 2;
    const int np = (kend - kbeg + 1) >> 1;

    f32x2 a0 = {0.f, 0.f}, a1 = a0, a2 = a0, a3 = a0,
          a4 = a0, a5 = a0, a6 = a0, a7 = a0;
    float lsum = 0.f;
    if (np > 0) {
        float tq[4];
        uint4 Ua[4], Ub[4];
        const int myk0 = kbeg + e;
        // preload stages s = edge myk0 + 2*s  (max idx kend-1+6 <= tot+5: padded)
#pragma unroll
        for (int s = 0; s < 4; s++) {
            unsigned j = elist[myk0 + 2 * s];
            tq[s] = trg[j * 8 + h];
            Ua[s] = *(const uint4*)(vb + (j << 10) + voffB);
            Ub[s] = *(const uint4*)(vb + (j << 10) + voffB + 16);
        }
        int myk = myk0;
#pragma unroll 4
        for (int kp = 0; kp < np; kp++) {
            const int s = kp & 3;
            // consume stage s
            float ev = sh + tq[s];
            ev = fmaxf(ev, 0.01f * ev);            // LeakyReLU
            float p = (myk < kend) ? __expf(ev) : 0.f;
            lsum += p;
            f32x2 p2 = {p, p};
            uint4 A = Ua[s], B = Ub[s];
            // refill stage s with edge myk+8 (max idx kend-1+8 = tot+7: padded)
            {
                unsigned jn = elist[myk + 8];
                tq[s] = trg[jn * 8 + h];
                Ua[s] = *(const uint4*)(vb + (jn << 10) + voffB);
                Ub[s] = *(const uint4*)(vb + (jn << 10) + voffB + 16);
            }
            f32x2 v0 = {__uint_as_float(A.x << 16), __uint_as_float(A.x & 0xffff0000u)};
            f32x2 v1 = {__uint_as_float(A.y << 16), __uint_as_float(A.y & 0xffff0000u)};
            f32x2 v2 = {__uint_as_float(A.z << 16), __uint_as_float(A.z & 0xffff0000u)};
            f32x2 v3 = {__uint_as_float(A.w << 16), __uint_as_float(A.w & 0xffff0000u)};
            f32x2 v4 = {__uint_as_float(B.x << 16), __uint_as_float(B.x & 0xffff0000u)};
            f32x2 v5 = {__uint_as_float(B.y << 16), __uint_as_float(B.y & 0xffff0000u)};
            f32x2 v6 = {__uint_as_float(B.z << 16), __uint_as_float(B.z & 0xffff0000u)};
            f32x2 v7 = {__uint_as_float(B.w << 16), __uint_as_float(B.w & 0xffff0000u)};
            a0 += p2 * v0;                         // v_pk_fma_f32
            a1 += p2 * v1;
            a2 += p2 * v2;
            a3 += p2 * v3;
            a4 += p2 * v4;
            a5 += p2 * v5;
            a6 += p2 * v6;
            a7 += p2 * v7;
            myk += 2;
        }
    }

    // ---- phase 3: cross-half, cross-wave combine; normalize; store ----
    float acc[16] = {a0.x, a0.y, a1.x, a1.y, a2.x, a2.y, a3.x, a3.y,
                     a4.x, a4.y, a5.x, a5.y, a6.x, a6.y, a7.x, a7.y};
#pragma unroll
    for (int r = 0; r < 16; r++) acc[r] += __shfl_xor(acc[r], 32, 64);
    lsum += __shfl_xor(lsum, 32, 64);

    if (w > 0 && e == 0) {
#pragma unroll
        for (int r = 0; r < 16; r++) cbuf[w - 1][l32][r] = acc[r];
        cbuf[w - 1][l32][16] = lsum;
    }
    __syncthreads();
    if (w == 0 && e == 0) {
#pragma unroll
        for (int wv = 0; wv < 3; wv++) {
#pragma unroll
            for (int r = 0; r < 16; r++) acc[r] += cbuf[wv][l32][r];
            lsum += cbuf[wv][l32][16];
        }
        float inv = (lsum > 0.f) ? (1.f / lsum) : 0.f;
        float* op = out + (size_t)i * HD + h * 64 + d4 * 16;
#pragma unroll
        for (int q = 0; q < 4; q++)
            *(float4*)(op + q * 4) = make_float4(acc[q * 4 + 0] * inv, acc[q * 4 + 1] * inv,
                                                 acc[q * 4 + 2] * inv, acc[q * 4 + 3] * inv);
    }
}

extern "C" void kernel_launch(void* const* d_in, const int* in_sizes, int n_in,
                              void* d_out, int out_size, void* d_ws, size_t ws_size,
                              hipStream_t stream) {
    const float* data = (const float*)d_in[0];   // (4096, 512)
    const float* conn = (const float*)d_in[1];   // (4096, 4096)
    const float* W    = (const float*)d_in[2];   // (512, 512)
    const float* bias = (const float*)d_in[3];   // (512,)
    const float* sp   = (const float*)d_in[4];   // (1, 8, 64)
    const float* tp   = (const float*)d_in[5];   // (1, 8, 64)
    float* out = (float*)d_out;                  // (4096, 512) fp32

    unsigned short* d1b = (unsigned short*)d_ws;              // 2M bf16 (4 MB)
    unsigned short* Ab  = d1b + (size_t)NN * HD;              // 2M bf16 (4 MB)
    unsigned short* Wb  = Ab + (size_t)NN * IN_DIM;           // 256K bf16 (512 KB)
    float* src  = (float*)(Wb + (size_t)HD * IN_DIM);         // 128 KB
    float* trg  = src + NN * NH;                              // 128 KB
    // total ~8.75 MB

    const int n4A = NN * IN_DIM / 4;   // 524288
    const int n4B = HD * IN_DIM / 4;   // 65536
    k_cast2<<<dim3((n4A + n4B + 255) / 256), 256, 0, stream>>>(data, Ab, n4A, W, Wb, n4B);
    k_gemm_fused<<<dim3(NH, NN / 64), 256, 0, stream>>>(Ab, Wb, bias, sp, tp, d1b, src, trg);
    k_rowattn<<<dim3(NN / 2), 256, 0, stream>>>(conn, src, trg, d1b, out, 0);
    k_rowattn<<<dim3(NN / 2), 256, 0, stream>>>(conn, src, trg, d1b, out, NN / 2);
}

// Round 12
// 169.780 us; speedup vs baseline: 2.8379x; 2.8379x over previous
//
#include <hip/hip_runtime.h>
#include <hip/hip_bf16.h>

#define NN 4096
#define IN_DIM 512
#define NH 8
#define DD 64
#define HD 512    // NH*DD
#define QCAP 128  // per-quarter cap: Binomial(1024,.05) mean 51 sigma 7 -> +11 sigma
#define RCAP 448  // per-row cap: mean 205 sigma 14 -> +17 sigma

// Workspace: d1b 4MB + Ab 4MB + Wb 0.5MB + src/trg 0.25MB ~= 8.75 MB
// (R3 lesson: stay well under ~12 MB; R7 proved 8.75 MB works).
// R11 lesson: NO dynamically-indexed local arrays in hot loops — they spill
// to scratch (478 MB WRITE_SIZE, 2.8x regression). Pipeline stages below are
// individually named variables with explicit rotation.

typedef __attribute__((ext_vector_type(8))) short short8;
typedef __attribute__((ext_vector_type(4))) float f32x4;
typedef __attribute__((ext_vector_type(2))) float f32x2;

static __device__ __forceinline__ unsigned short f2bf(float x) {
    __hip_bfloat16 h = __float2bfloat16(x);
    return *reinterpret_cast<unsigned short*>(&h);
}

// ---------------- K0: fp32 -> bf16 cast of data and W (one launch) -----------
__global__ __launch_bounds__(256) void k_cast2(const float* __restrict__ inA,
                                               unsigned short* __restrict__ outA,
                                               int n4A,
                                               const float* __restrict__ inB,
                                               unsigned short* __restrict__ outB,
                                               int n4B) {
    int t = blockIdx.x * 256 + threadIdx.x;
    const float* in;
    unsigned short* out;
    if (t < n4A) {
        in = inA; out = outA;
    } else {
        t -= n4A;
        if (t >= n4B) return;
        in = inB; out = outB;
    }
    float4 v = ((const float4*)in)[t];
    ushort4 o;
    o.x = f2bf(v.x); o.y = f2bf(v.y); o.z = f2bf(v.z); o.w = f2bf(v.w);
    ((ushort4*)out)[t] = o;
}

// ---------------- K1: GEMM (bf16 MFMA) + fused src/trg projection ------------
// 64n x 64m per WG; m-tile == one head h = blockIdx.x. Fragments straight
// from global (k-major). C/D: col=lane&15, row=(lane>>4)*4+reg (m89-verified).
__global__ __launch_bounds__(256) void k_gemm_fused(const unsigned short* __restrict__ Ab,
                                                    const unsigned short* __restrict__ Wb,
                                                    const float* __restrict__ bias,
                                                    const float* __restrict__ sp,
                                                    const float* __restrict__ tp,
                                                    unsigned short* __restrict__ Cb,
                                                    float* __restrict__ src,
                                                    float* __restrict__ trg) {
    const int lane = threadIdx.x & 63;
    const int w = threadIdx.x >> 6;
    const int col = lane & 15;
    const int quad = lane >> 4;
    const int koff = quad * 8;
    const int h = blockIdx.x;
    const int m0 = h * 64;
    const int n0 = blockIdx.y * 64;

    const short8* ap  = (const short8*)(Ab + (size_t)(n0 + w * 16 + col) * IN_DIM + koff);
    const short8* bp0 = (const short8*)(Wb + (size_t)(m0 +  0 + col) * IN_DIM + koff);
    const short8* bp1 = (const short8*)(Wb + (size_t)(m0 + 16 + col) * IN_DIM + koff);
    const short8* bp2 = (const short8*)(Wb + (size_t)(m0 + 32 + col) * IN_DIM + koff);
    const short8* bp3 = (const short8*)(Wb + (size_t)(m0 + 48 + col) * IN_DIM + koff);

    f32x4 acc0 = {0.f, 0.f, 0.f, 0.f}, acc1 = acc0, acc2 = acc0, acc3 = acc0;

#pragma unroll 4
    for (int ks = 0; ks < 16; ks++) {
        short8 a  = ap[ks * 4];
        short8 b0 = bp0[ks * 4];
        short8 b1 = bp1[ks * 4];
        short8 b2 = bp2[ks * 4];
        short8 b3 = bp3[ks * 4];
        acc0 = __builtin_amdgcn_mfma_f32_16x16x32_bf16(a, b0, acc0, 0, 0, 0);
        acc1 = __builtin_amdgcn_mfma_f32_16x16x32_bf16(a, b1, acc1, 0, 0, 0);
        acc2 = __builtin_amdgcn_mfma_f32_16x16x32_bf16(a, b2, acc2, 0, 0, 0);
        acc3 = __builtin_amdgcn_mfma_f32_16x16x32_bf16(a, b3, acc3, 0, 0, 0);
    }

    const int rbase = n0 + w * 16 + quad * 4;
    f32x4 accs[4] = {acc0, acc1, acc2, acc3};
    float ps[4] = {0.f, 0.f, 0.f, 0.f};
    float pt[4] = {0.f, 0.f, 0.f, 0.f};
#pragma unroll
    for (int mt = 0; mt < 4; mt++) {
        const int m = m0 + mt * 16 + col;
        const float bv  = bias[m];
        const float spv = sp[m];
        const float tpv = tp[m];
#pragma unroll
        for (int r = 0; r < 4; r++) {
            float v = accs[mt][r] + bv;
            Cb[(size_t)(rbase + r) * HD + m] = f2bf(v);
            ps[r] += v * spv;
            pt[r] += v * tpv;
        }
    }
#pragma unroll
    for (int off = 1; off <= 8; off <<= 1) {
#pragma unroll
        for (int r = 0; r < 4; r++) {
            ps[r] += __shfl_xor(ps[r], off, 64);
            pt[r] += __shfl_xor(pt[r], off, 64);
        }
    }
    if (col < 4)
        src[(rbase + col) * 8 + h] = ps[col];
    else if (col < 8)
        trg[(rbase + col - 4) * 8 + h] = pt[col - 4];
}

// ---------------- K2: fused edge-scan + 2-edge-split gather attention --------
// One WG (4 waves) per row i.
//  phase 1: per-wave ballot-scan of a conn quarter into LDS segment.
//  phase 1b: compact to one list + 8 sentinels (no clamps needed anywhere).
//  phase 2: wave w gathers balanced range; lane = (e, h, d4): half-wave e
//           processes edge kbeg+2*kp+e, lane holds 32B (16 bf16) of V row.
//           Depth-3 V pipeline with NAMED stage registers (t0..t3, U0..U3),
//           explicit rotation, unroll 3 (renaming kills the movs). R11's
//           array-indexed stages spilled to scratch — never again.
//  phase 3: shfl_xor(32) cross-half combine, LDS cross-wave combine,
//           divide once, store.
// conn==0.0f exactly marks kept edges; |e|<~6 so no max-subtraction needed.
__global__ __launch_bounds__(256) void k_rowattn(const float* __restrict__ conn,
                                                 const float* __restrict__ src,
                                                 const float* __restrict__ trg,
                                                 const unsigned short* __restrict__ d1b,
                                                 float* __restrict__ out) {
    __shared__ unsigned short seg[4][QCAP];
    __shared__ unsigned short elist[RCAP + 8];
    __shared__ int wcnt[4];
    __shared__ float cbuf[3][32][17];   // waves 1..3 deposit acc[16]+lsum
    const int w = threadIdx.x >> 6, lane = threadIdx.x & 63;
    const int i = blockIdx.x;

    // ---- phase 1: scan this wave's quarter of the conn row ----
    const float* crow = conn + (size_t)i * NN + w * 1024;
    int cnt = 0;
#pragma unroll
    for (int c0 = 0; c0 < 1024; c0 += 256) {
        float4 c = *(const float4*)(crow + c0 + lane * 4);
        float cv[4] = {c.x, c.y, c.z, c.w};
#pragma unroll
        for (int q = 0; q < 4; q++) {
            bool edge = (cv[q] == 0.0f);
            unsigned long long mask = __ballot(edge);
            int pre = __popcll(mask & ((1ull << lane) - 1ull));
            int pos = cnt + pre;
            if (edge && pos < QCAP)
                seg[w][pos] = (unsigned short)(w * 1024 + c0 + lane * 4 + q);
            cnt += __popcll(mask);
        }
    }
    if (cnt > QCAP) cnt = QCAP;
    if (lane == 0) wcnt[w] = cnt;
    __syncthreads();

    // ---- phase 1b: compact into one contiguous list + 8 sentinels ----
    const int c0n = wcnt[0], c1n = wcnt[1], c2n = wcnt[2], c3n = wcnt[3];
    int tot = c0n + c1n + c2n + c3n;
    if (tot > RCAP) tot = RCAP;   // (unreachable in practice)
    const int base = (w == 0) ? 0 : (w == 1) ? c0n
                   : (w == 2) ? c0n + c1n : c0n + c1n + c2n;
    for (int k = lane; k < cnt && base + k < RCAP; k += 64)
        elist[base + k] = seg[w][k];
    __syncthreads();
    if (threadIdx.x < 8)
        elist[tot + threadIdx.x] = (tot > 0) ? elist[tot - 1] : (unsigned short)0;
    __syncthreads();

    // ---- phase 2: balanced gather, 2 edges/iter, depth-3 named pipeline ----
    const int e = lane >> 5;          // which edge of the pair
    const int l32 = lane & 31;
    const int h = l32 >> 2;           // 8 heads
    const int d4 = l32 & 3;           // 4 chunks of 16 bf16
    const float sh = src[i * 8 + h];
    const unsigned voffB = (unsigned)(h * 128 + d4 * 32);
    const unsigned char* vb = (const unsigned char*)d1b;
    const int kbeg = (tot * w) >> 2;
    const int kend = (tot * (w + 1)) >> 2;
    const int np = (kend - kbeg + 1) >> 1;

    f32x2 a0 = {0.f, 0.f}, a1 = a0, a2 = a0, a3 = a0,
          a4 = a0, a5 = a0, a6 = a0, a7 = a0;
    float lsum = 0.f;
    if (np > 0) {
        int myk = kbeg + e;
        // preload 3 named stages (edges myk, myk+2, myk+4; sentinels cover OOB)
        unsigned j0 = elist[myk];
        unsigned j1 = elist[myk + 2];
        unsigned j2 = elist[myk + 4];
        float t0 = trg[j0 * 8 + h];
        float t1 = trg[j1 * 8 + h];
        float t2 = trg[j2 * 8 + h];
        uint4 U0a = *(const uint4*)(vb + (j0 << 10) + voffB);
        uint4 U0b = *(const uint4*)(vb + (j0 << 10) + voffB + 16);
        uint4 U1a = *(const uint4*)(vb + (j1 << 10) + voffB);
        uint4 U1b = *(const uint4*)(vb + (j1 << 10) + voffB + 16);
        uint4 U2a = *(const uint4*)(vb + (j2 << 10) + voffB);
        uint4 U2b = *(const uint4*)(vb + (j2 << 10) + voffB + 16);
#pragma unroll 3
        for (int kp = 0; kp < np; kp++) {
            // fetch stage 3 (edge myk+6; max idx kend-1+6 <= tot+5: padded)
            unsigned j3 = elist[myk + 6];
            float t3 = trg[j3 * 8 + h];
            uint4 U3a = *(const uint4*)(vb + (j3 << 10) + voffB);
            uint4 U3b = *(const uint4*)(vb + (j3 << 10) + voffB + 16);
            // consume stage 0
            float ev = sh + t0;
            ev = fmaxf(ev, 0.01f * ev);            // LeakyReLU
            float p = (myk < kend) ? __expf(ev) : 0.f;
            lsum += p;
            f32x2 p2 = {p, p};
            f32x2 v0 = {__uint_as_float(U0a.x << 16), __uint_as_float(U0a.x & 0xffff0000u)};
            f32x2 v1 = {__uint_as_float(U0a.y << 16), __uint_as_float(U0a.y & 0xffff0000u)};
            f32x2 v2 = {__uint_as_float(U0a.z << 16), __uint_as_float(U0a.z & 0xffff0000u)};
            f32x2 v3 = {__uint_as_float(U0a.w << 16), __uint_as_float(U0a.w & 0xffff0000u)};
            f32x2 v4 = {__uint_as_float(U0b.x << 16), __uint_as_float(U0b.x & 0xffff0000u)};
            f32x2 v5 = {__uint_as_float(U0b.y << 16), __uint_as_float(U0b.y & 0xffff0000u)};
            f32x2 v6 = {__uint_as_float(U0b.z << 16), __uint_as_float(U0b.z & 0xffff0000u)};
            f32x2 v7 = {__uint_as_float(U0b.w << 16), __uint_as_float(U0b.w & 0xffff0000u)};
            a0 += p2 * v0;                         // v_pk_fma_f32
            a1 += p2 * v1;
            a2 += p2 * v2;
            a3 += p2 * v3;
            a4 += p2 * v4;
            a5 += p2 * v5;
            a6 += p2 * v6;
            a7 += p2 * v7;
            // rotate named stages (unroll-3 renames these away)
            t0 = t1; t1 = t2; t2 = t3;
            U0a = U1a; U0b = U1b;
            U1a = U2a; U1b = U2b;
            U2a = U3a; U2b = U3b;
            myk += 2;
        }
    }

    // ---- phase 3: cross-half, cross-wave combine; normalize; store ----
    float acc[16] = {a0.x, a0.y, a1.x, a1.y, a2.x, a2.y, a3.x, a3.y,
                     a4.x, a4.y, a5.x, a5.y, a6.x, a6.y, a7.x, a7.y};
#pragma unroll
    for (int r = 0; r < 16; r++) acc[r] += __shfl_xor(acc[r], 32, 64);
    lsum += __shfl_xor(lsum, 32, 64);

    if (w > 0 && e == 0) {
#pragma unroll
        for (int r = 0; r < 16; r++) cbuf[w - 1][l32][r] = acc[r];
        cbuf[w - 1][l32][16] = lsum;
    }
    __syncthreads();
    if (w == 0 && e == 0) {
#pragma unroll
        for (int wv = 0; wv < 3; wv++) {
#pragma unroll
            for (int r = 0; r < 16; r++) acc[r] += cbuf[wv][l32][r];
            lsum += cbuf[wv][l32][16];
        }
        float inv = (lsum > 0.f) ? (1.f / lsum) : 0.f;
        float* op = out + (size_t)i * HD + h * 64 + d4 * 16;
#pragma unroll
        for (int q = 0; q < 4; q++)
            *(float4*)(op + q * 4) = make_float4(acc[q * 4 + 0] * inv, acc[q * 4 + 1] * inv,
                                                 acc[q * 4 + 2] * inv, acc[q * 4 + 3] * inv);
    }
}

extern "C" void kernel_launch(void* const* d_in, const int* in_sizes, int n_in,
                              void* d_out, int out_size, void* d_ws, size_t ws_size,
                              hipStream_t stream) {
    const float* data = (const float*)d_in[0];   // (4096, 512)
    const float* conn = (const float*)d_in[1];   // (4096, 4096)
    const float* W    = (const float*)d_in[2];   // (512, 512)
    const float* bias = (const float*)d_in[3];   // (512,)
    const float* sp   = (const float*)d_in[4];   // (1, 8, 64)
    const float* tp   = (const float*)d_in[5];   // (1, 8, 64)
    float* out = (float*)d_out;                  // (4096, 512) fp32

    unsigned short* d1b = (unsigned short*)d_ws;              // 2M bf16 (4 MB)
    unsigned short* Ab  = d1b + (size_t)NN * HD;              // 2M bf16 (4 MB)
    unsigned short* Wb  = Ab + (size_t)NN * IN_DIM;           // 256K bf16 (512 KB)
    float* src  = (float*)(Wb + (size_t)HD * IN_DIM);         // 128 KB
    float* trg  = src + NN * NH;                              // 128 KB
    // total ~8.75 MB

    const int n4A = NN * IN_DIM / 4;   // 524288
    const int n4B = HD * IN_DIM / 4;   // 65536
    k_cast2<<<dim3((n4A + n4B + 255) / 256), 256, 0, stream>>>(data, Ab, n4A, W, Wb, n4B);
    k_gemm_fused<<<dim3(NH, NN / 64), 256, 0, stream>>>(Ab, Wb, bias, sp, tp, d1b, src, trg);
    k_rowattn<<<dim3(NN), 256, 0, stream>>>(conn, src, trg, d1b, out);
}